// Round 11
// baseline (168.996 us; speedup 1.0000x reference)
//
#include <hip/hip_runtime.h>
#include <hip/hip_bf16.h>
#include <math.h>

// ---------------------------------------------------------------------------
// FASA pipeline for MI355X. B=4, C=128, H=W=128, HEADS=4, dh=32, pool->32x32
// Round 11: 256-thr split-K attn; LDS-free GEMMs (pre-converted bf16 W);
// gf stored bf16.
// ---------------------------------------------------------------------------

#define NB   4
#define NC   128
#define NH   128
#define NW   128
#define NHW  16384      // 128*128
#define NKV  1024       // 32*32

typedef float    f32x4  __attribute__((ext_vector_type(4)));
typedef float    f32x16 __attribute__((ext_vector_type(16)));
typedef short    bf16x8 __attribute__((ext_vector_type(8)));
typedef short    bf16x4 __attribute__((ext_vector_type(4)));
typedef unsigned u32x4v __attribute__((ext_vector_type(4)));

__device__ __forceinline__ unsigned short f2bf(float f) {
  unsigned u = __float_as_uint(f);
  u += 0x7FFF + ((u >> 16) & 1);      // round to nearest even
  return (unsigned short)(u >> 16);
}

__device__ __forceinline__ float bf2f(unsigned short u) {
  return __uint_as_float((unsigned)u << 16);
}

// pack two f32 -> bf16x2 in one instr (no builtin on gfx950; T12 recipe)
__device__ __forceinline__ unsigned cvtpk(float lo, float hi) {
  unsigned r;
  asm("v_cvt_pk_bf16_f32 %0, %1, %2" : "=v"(r) : "v"(lo), "v"(hi));
  return r;
}

// ---------------------------------------------------------------------------
// Weight convert: concat {q_w(16384), lin0_w(16384), kv_w(32768), mixer_w(16384)}
// fp32 -> bf16 once. 80 blocks x 256 thr x 4 elems.
// ---------------------------------------------------------------------------
__global__ __launch_bounds__(256) void wcvt(
    const float* __restrict__ a, const float* __restrict__ bsrc,
    const float* __restrict__ csrc, const float* __restrict__ dsrc,
    unsigned short* __restrict__ o)
{
  int base = (blockIdx.x * 256 + threadIdx.x) * 4;
  float4 v;
  if (base < 16384)        v = *(const float4*)&a[base];
  else if (base < 32768)   v = *(const float4*)&bsrc[base - 16384];
  else if (base < 65536)   v = *(const float4*)&csrc[base - 32768];
  else                     v = *(const float4*)&dsrc[base - 65536];
  uint2 pk; pk.x = cvtpk(v.x, v.y); pk.y = cvtpk(v.z, v.w);
  *(uint2*)&o[base] = pk;
}

// ---------------------------------------------------------------------------
// MFMA pointwise 1x1 conv, LDS-free: Wbf is bf16 [Mtot][128] (L2-resident).
// Block: 128 M x 128 N, 4 waves; wave w owns N cols w*32..w*32+31.
// ---------------------------------------------------------------------------
template<bool IN_BF16, bool OUT_BF16>
__global__ __launch_bounds__(256) void pw_gemm_mfma(
    const unsigned short* __restrict__ Wbf,  // [Mtot][128] bf16
    const float* __restrict__ bias,          // [Mtot]
    const void* __restrict__ Xv,             // [B][128][npos]
    void* __restrict__ Yv,                   // [B][Mtot][npos]
    int npos, int Mtot)
{
  const int t  = threadIdx.x;
  const int w    = t >> 6;
  const int lane = t & 63;
  const int nl   = lane & 31;
  const int hi   = lane >> 5;
  const int b  = blockIdx.z;
  const int m0 = blockIdx.y * 128;
  const int n0 = blockIdx.x * 128;

  f32x16 acc[4];
  #pragma unroll
  for (int mg = 0; mg < 4; mg++)
    #pragma unroll
    for (int r = 0; r < 16; r++) acc[mg][r] = 0.f;

  #pragma unroll
  for (int s = 0; s < 8; s++) {
    bf16x8 bfrag;
    if constexpr (IN_BF16) {
      const unsigned short* Xb = (const unsigned short*)Xv
          + (size_t)b * 128 * npos + n0 + w * 32 + nl;
      const unsigned short* xp = Xb + (size_t)(s * 16 + hi * 8) * npos;
      #pragma unroll
      for (int e = 0; e < 8; e++) bfrag[e] = (short)xp[(size_t)e * npos];
    } else {
      const float* Xb = (const float*)Xv + (size_t)b * 128 * npos + n0 + w * 32 + nl;
      const float* xp = Xb + (size_t)(s * 16 + hi * 8) * npos;
      float xv[8];
      #pragma unroll
      for (int e = 0; e < 8; e++) xv[e] = xp[(size_t)e * npos];
      u32x4v bu;
      #pragma unroll
      for (int j = 0; j < 4; j++) bu[j] = cvtpk(xv[2 * j], xv[2 * j + 1]);
      bfrag = __builtin_bit_cast(bf16x8, bu);
    }

    #pragma unroll
    for (int mg = 0; mg < 4; mg++) {
      bf16x8 afrag = *(const bf16x8*)&Wbf[(size_t)(m0 + mg * 32 + nl) * 128 + s * 16 + hi * 8];
      acc[mg] = __builtin_amdgcn_mfma_f32_32x32x16_bf16(afrag, bfrag, acc[mg], 0, 0, 0);
    }
  }

  #pragma unroll
  for (int mg = 0; mg < 4; mg++)
    #pragma unroll
    for (int r = 0; r < 16; r++) {
      int drow = mg * 32 + (r & 3) + 8 * (r >> 2) + 4 * hi;
      float val = acc[mg][r] + bias[m0 + drow];
      if constexpr (OUT_BF16) {
        unsigned short* Yb = (unsigned short*)Yv
            + ((size_t)b * Mtot + m0) * npos + n0 + w * 32 + nl;
        Yb[(size_t)drow * npos] = f2bf(val);
      } else {
        float* Yb = (float*)Yv + ((size_t)b * Mtot + m0) * npos + n0 + w * 32 + nl;
        Yb[(size_t)drow * npos] = val;
      }
    }
}

// ---------------------------------------------------------------------------
// LDS-tiled stride-2 depthwise 5x5 + BN.
// ---------------------------------------------------------------------------
template<int INH, int INW, int OUTW, int ORPB, int WLSP>
__global__ __launch_bounds__(256) void dw5x5s2_tile(
    const float* __restrict__ in,
    const float* __restrict__ wt, const float* __restrict__ bias,
    const float* __restrict__ g, const float* __restrict__ bt,
    const float* __restrict__ mean, const float* __restrict__ var,
    float* __restrict__ out)
{
  constexpr int IR = 2 * ORPB + 3;
  constexpr int XG = OUTW / 4;
  __shared__ float Ls[IR * WLSP];

  const int t  = threadIdx.x;
  const int c  = blockIdx.y, b = blockIdx.z;
  const int y0 = blockIdx.x * ORPB;
  const float* plane = in + ((size_t)b * NC + c) * INH * INW;

  for (int i = t; i < IR * WLSP / 4; i += 256)
    *(float4*)&Ls[i * 4] = (float4){0.f, 0.f, 0.f, 0.f};
  __syncthreads();

  for (int i = t; i < IR * (INW / 4); i += 256) {
    int r = i / (INW / 4), s4 = (i % (INW / 4)) * 4;
    int gy = 2 * y0 - 2 + r;
    if (gy >= 0 && gy < INH)
      *(float4*)&Ls[r * WLSP + 4 + s4] = *(const float4*)&plane[(size_t)gy * INW + s4];
  }

  float wreg[25];
  #pragma unroll
  for (int i = 0; i < 25; i++) wreg[i] = wt[c * 25 + i];
  const float sc = g[c] * rsqrtf(var[c] + 1e-5f);
  const float off = (bias[c] - mean[c]) * sc + bt[c];
  __syncthreads();

  const int row = t / XG;
  const int x0  = (t % XG) * 4;
  const int r0  = 2 * row;

  float a[4] = {0.f, 0.f, 0.f, 0.f};
  #pragma unroll
  for (int i = 0; i < 5; i++) {
    const float* lr = &Ls[(r0 + i) * WLSP + 2 * x0];
    float4 L0 = *(const float4*)&lr[0];
    float4 L1 = *(const float4*)&lr[4];
    float4 L2 = *(const float4*)&lr[8];
    float4 L3 = *(const float4*)&lr[12];
    float rr[16] = {L0.x,L0.y,L0.z,L0.w, L1.x,L1.y,L1.z,L1.w,
                    L2.x,L2.y,L2.z,L2.w, L3.x,L3.y,L3.z,L3.w};
    #pragma unroll
    for (int j = 0; j < 5; j++) {
      float wv = wreg[i * 5 + j];
      #pragma unroll
      for (int o = 0; o < 4; o++)
        a[o] += wv * rr[2 * o + j + 2];
    }
  }

  float4 ov;
  ov.x = a[0] * sc + off; ov.y = a[1] * sc + off;
  ov.z = a[2] * sc + off; ov.w = a[3] * sc + off;
  const int OH = INH / 2;
  *(float4*)&out[((size_t)b * NC + c) * OH * OUTW + (size_t)(y0 + row) * OUTW + x0] = ov;
}

// ---------------------------------------------------------------------------
// kv prep: kvb fp32 [4][256][1024] -> kT bf16 [16][1024][32], vT bf16 [16][32][1024]
// ---------------------------------------------------------------------------
__global__ __launch_bounds__(256) void kv_prep(
    const float* __restrict__ kvb,
    short* __restrict__ kT, short* __restrict__ vT)
{
  const int t = threadIdx.x;
  const int h = blockIdx.y, b = blockIdx.z;
  const int kpos = blockIdx.x * 256 + t;
  const int bh = b * 4 + h;

  bf16x8 kr[4];
  #pragma unroll
  for (int d = 0; d < 32; d++) {
    float kvv = kvb[((size_t)b * 256 + h * 32 + d) * NKV + kpos];
    float vvv = kvb[((size_t)b * 256 + 128 + h * 32 + d) * NKV + kpos];
    kr[d >> 3][d & 7] = (short)f2bf(kvv);
    vT[(size_t)bh * 32768 + d * NKV + kpos] = (short)f2bf(vvv);
  }
  short* dstk = kT + (size_t)bh * 32768 + (size_t)kpos * 32;
  #pragma unroll
  for (int i = 0; i < 4; i++)
    *(bf16x8*)(dstk + i * 8) = kr[i];
}

// ---------------------------------------------------------------------------
// Split-K dual-query 32x32 MFMA flash attention, 256 thr = 4 waves:
// wave w -> query group (w&1: 64 q), key half (w>>1). R9/R10-proven body.
// Output gf stored bf16.
// ---------------------------------------------------------------------------
__global__ __launch_bounds__(256) void attn_mfma64(
    const unsigned short* __restrict__ q16,  // [4][128][16384] bf16
    const short* __restrict__ kT,            // [16][1024][32] bf16
    const short* __restrict__ vT,            // [16][32][1024] bf16
    unsigned short* __restrict__ gf16)       // [4][128][16384] bf16
{
  __shared__ float Cmb[2][64][34];

  const int t    = threadIdx.x;
  const int w    = t >> 6;          // 0..3
  const int lane = t & 63;
  const int c    = lane & 31;
  const int hi   = lane >> 5;
  const int qg   = w & 1;
  const int half = w >> 1;
  const int b    = blockIdx.z, h = blockIdx.y;
  const int q0   = blockIdx.x * 128 + qg * 64;
  const int bh   = b * 4 + h;
  const int kbase = half * 512;     // first key of this half

  const float QSCALE = 0.17677669529663689f * 1.4426950408889634f; // scale*log2e

  // Q^T B-operand frags for columns q0+c (A) and q0+32+c (B), from bf16
  bf16x8 qA1, qA2, qB1, qB2;
  {
    const unsigned short* qb = q16 + ((size_t)(b * NC + h * 32 + hi * 8)) * NHW + q0 + c;
    float fva[16], fvb[16];
    #pragma unroll
    for (int e = 0; e < 8; e++) {
      fva[e]     = bf2f(qb[(size_t)e * NHW]) * QSCALE;
      fva[8 + e] = bf2f(qb[(size_t)(16 + e) * NHW]) * QSCALE;
      fvb[e]     = bf2f(qb[(size_t)e * NHW + 32]) * QSCALE;
      fvb[8 + e] = bf2f(qb[(size_t)(16 + e) * NHW + 32]) * QSCALE;
    }
    u32x4v u1, u2, u3, u4;
    #pragma unroll
    for (int j = 0; j < 4; j++) {
      u1[j] = cvtpk(fva[2 * j], fva[2 * j + 1]);
      u2[j] = cvtpk(fva[8 + 2 * j], fva[9 + 2 * j]);
      u3[j] = cvtpk(fvb[2 * j], fvb[2 * j + 1]);
      u4[j] = cvtpk(fvb[8 + 2 * j], fvb[9 + 2 * j]);
    }
    qA1 = __builtin_bit_cast(bf16x8, u1); qA2 = __builtin_bit_cast(bf16x8, u2);
    qB1 = __builtin_bit_cast(bf16x8, u3); qB2 = __builtin_bit_cast(bf16x8, u4);
  }

  const short* kbh = kT + (size_t)bh * 32768;
  const short* vbh = vT + (size_t)bh * 32768;

  f32x16 oA, oB;
  #pragma unroll
  for (int r = 0; r < 16; r++) { oA[r] = 0.f; oB[r] = 0.f; }
  const f32x16 zf = oA;
  float lsumA = 0.f, lsumB = 0.f;

  bf16x8 ka  = *(const bf16x8*)(kbh + (size_t)(kbase + c) * 32 + hi * 8);
  bf16x8 kb2 = *(const bf16x8*)(kbh + (size_t)(kbase + c) * 32 + 16 + hi * 8);
  bf16x8 va  = *(const bf16x8*)(vbh + (size_t)c * NKV + kbase + hi * 8);
  bf16x8 vb2 = *(const bf16x8*)(vbh + (size_t)c * NKV + kbase + 16 + hi * 8);

  for (int kt = 0; kt < 16; kt++) {
    const int k0n = (kt < 15) ? (kbase + (kt + 1) * 32) : 0;
    bf16x8 nka  = *(const bf16x8*)(kbh + (size_t)(k0n + c) * 32 + hi * 8);
    bf16x8 nkb  = *(const bf16x8*)(kbh + (size_t)(k0n + c) * 32 + 16 + hi * 8);
    bf16x8 nva  = *(const bf16x8*)(vbh + (size_t)c * NKV + k0n + hi * 8);
    bf16x8 nvb  = *(const bf16x8*)(vbh + (size_t)c * NKV + k0n + 16 + hi * 8);

    // ---- column set A ----
    {
      f32x16 s = __builtin_amdgcn_mfma_f32_32x32x16_bf16(ka,  qA1, zf, 0, 0, 0);
      s        = __builtin_amdgcn_mfma_f32_32x32x16_bf16(kb2, qA2, s,  0, 0, 0);
      float p[16];
      #pragma unroll
      for (int r = 0; r < 16; r++) p[r] = __builtin_amdgcn_exp2f(s[r]);
      float s0 = (p[0] + p[1]) + (p[2] + p[3]);
      float s1 = (p[4] + p[5]) + (p[6] + p[7]);
      float s2 = (p[8] + p[9]) + (p[10] + p[11]);
      float s3 = (p[12] + p[13]) + (p[14] + p[15]);
      lsumA += (s0 + s1) + (s2 + s3);

      unsigned a0 = cvtpk(p[0],  p[1]);
      unsigned a1 = cvtpk(p[2],  p[3]);
      unsigned a2 = cvtpk(p[4],  p[5]);
      unsigned a3 = cvtpk(p[6],  p[7]);
      unsigned a4 = cvtpk(p[8],  p[9]);
      unsigned a5 = cvtpk(p[10], p[11]);
      unsigned a6 = cvtpk(p[12], p[13]);
      unsigned a7 = cvtpk(p[14], p[15]);
      asm("v_permlane32_swap_b32 %0, %1" : "+v"(a0), "+v"(a2));
      asm("v_permlane32_swap_b32 %0, %1" : "+v"(a1), "+v"(a3));
      asm("v_permlane32_swap_b32 %0, %1" : "+v"(a4), "+v"(a6));
      asm("v_permlane32_swap_b32 %0, %1" : "+v"(a5), "+v"(a7));
      u32x4v b1u = {a0, a1, a2, a3};
      u32x4v b2u = {a4, a5, a6, a7};
      bf16x8 pb1 = __builtin_bit_cast(bf16x8, b1u);
      bf16x8 pb2 = __builtin_bit_cast(bf16x8, b2u);
      oA = __builtin_amdgcn_mfma_f32_32x32x16_bf16(va,  pb1, oA, 0, 0, 0);
      oA = __builtin_amdgcn_mfma_f32_32x32x16_bf16(vb2, pb2, oA, 0, 0, 0);
    }

    // ---- column set B ----
    {
      f32x16 s = __builtin_amdgcn_mfma_f32_32x32x16_bf16(ka,  qB1, zf, 0, 0, 0);
      s        = __builtin_amdgcn_mfma_f32_32x32x16_bf16(kb2, qB2, s,  0, 0, 0);
      float p[16];
      #pragma unroll
      for (int r = 0; r < 16; r++) p[r] = __builtin_amdgcn_exp2f(s[r]);
      float s0 = (p[0] + p[1]) + (p[2] + p[3]);
      float s1 = (p[4] + p[5]) + (p[6] + p[7]);
      float s2 = (p[8] + p[9]) + (p[10] + p[11]);
      float s3 = (p[12] + p[13]) + (p[14] + p[15]);
      lsumB += (s0 + s1) + (s2 + s3);

      unsigned a0 = cvtpk(p[0],  p[1]);
      unsigned a1 = cvtpk(p[2],  p[3]);
      unsigned a2 = cvtpk(p[4],  p[5]);
      unsigned a3 = cvtpk(p[6],  p[7]);
      unsigned a4 = cvtpk(p[8],  p[9]);
      unsigned a5 = cvtpk(p[10], p[11]);
      unsigned a6 = cvtpk(p[12], p[13]);
      unsigned a7 = cvtpk(p[14], p[15]);
      asm("v_permlane32_swap_b32 %0, %1" : "+v"(a0), "+v"(a2));
      asm("v_permlane32_swap_b32 %0, %1" : "+v"(a1), "+v"(a3));
      asm("v_permlane32_swap_b32 %0, %1" : "+v"(a4), "+v"(a6));
      asm("v_permlane32_swap_b32 %0, %1" : "+v"(a5), "+v"(a7));
      u32x4v b1u = {a0, a1, a2, a3};
      u32x4v b2u = {a4, a5, a6, a7};
      bf16x8 pb1 = __builtin_bit_cast(bf16x8, b1u);
      bf16x8 pb2 = __builtin_bit_cast(bf16x8, b2u);
      oB = __builtin_amdgcn_mfma_f32_32x32x16_bf16(va,  pb1, oB, 0, 0, 0);
      oB = __builtin_amdgcn_mfma_f32_32x32x16_bf16(vb2, pb2, oB, 0, 0, 0);
    }

    ka = nka; kb2 = nkb; va = nva; vb2 = nvb;
  }

  // combine halves through LDS: half1 deposits, half0 reduces + stores
  if (half) {
    float* dst = &Cmb[qg][lane][0];
    #pragma unroll
    for (int r = 0; r < 16; r++) { dst[r] = oA[r]; dst[16 + r] = oB[r]; }
    dst[32] = lsumA; dst[33] = lsumB;
  }
  __syncthreads();
  if (!half) {
    const float* src = &Cmb[qg][lane][0];
    #pragma unroll
    for (int r = 0; r < 16; r++) { oA[r] += src[r]; oB[r] += src[16 + r]; }
    lsumA += src[32]; lsumB += src[33];

    lsumA += __shfl_xor(lsumA, 32);
    lsumB += __shfl_xor(lsumB, 32);
    float invA = 1.f / lsumA;
    float invB = 1.f / lsumB;

    unsigned short* gfb = gf16 + ((size_t)(b * NC + h * 32)) * NHW + q0 + c;
    #pragma unroll
    for (int r = 0; r < 16; r++) {
      int d = (r & 3) + 8 * (r >> 2) + 4 * hi;
      gfb[(size_t)d * NHW]      = f2bf(oA[r] * invA);
      gfb[(size_t)d * NHW + 32] = f2bf(oB[r] * invB);
    }
  }
}

// ---------------------------------------------------------------------------
// LDS-tiled lf_fuse: lf = dw5x5_s1(q16)+local_b; t16 = bf16(lf*sig(lf)*sig(gf)*gf)
// q16/gf16 bf16 inputs.
// ---------------------------------------------------------------------------
__global__ __launch_bounds__(256) void lf_fuse_tile(
    const unsigned short* __restrict__ q16, const unsigned short* __restrict__ gf16,
    const float* __restrict__ wt, const float* __restrict__ bias,
    unsigned short* __restrict__ t16)
{
  __shared__ float Ls[12 * 140];

  const int t  = threadIdx.x;
  const int c  = blockIdx.y, b = blockIdx.z;
  const int y0 = blockIdx.x * 8;
  const unsigned short* plane = q16 + ((size_t)b * NC + c) * NHW;

  for (int i = t; i < 12 * 140 / 4; i += 256)
    *(float4*)&Ls[i * 4] = (float4){0.f, 0.f, 0.f, 0.f};
  __syncthreads();

  for (int i = t; i < 12 * 16; i += 256) {
    int r = i >> 4, s8 = (i & 15) * 8;
    int gy = y0 - 2 + r;
    if (gy >= 0 && gy < NH) {
      bf16x8 v = *(const bf16x8*)&plane[(size_t)gy * NW + s8];
      float* dp = &Ls[r * 140 + 4 + s8];
      #pragma unroll
      for (int j = 0; j < 8; j++) dp[j] = bf2f((unsigned short)v[j]);
    }
  }

  float wreg[25];
  #pragma unroll
  for (int i = 0; i < 25; i++) wreg[i] = wt[c * 25 + i];
  const float bs = bias[c];
  __syncthreads();

  const int row = t >> 5;
  const int x0  = (t & 31) * 4;

  float a[4] = {bs, bs, bs, bs};
  #pragma unroll
  for (int i = 0; i < 5; i++) {
    const float* lr = &Ls[(row + i) * 140 + x0];
    float4 L0 = *(const float4*)&lr[0];
    float4 L1 = *(const float4*)&lr[4];
    float4 L2 = *(const float4*)&lr[8];
    float rr[12] = {L0.x,L0.y,L0.z,L0.w, L1.x,L1.y,L1.z,L1.w,
                    L2.x,L2.y,L2.z,L2.w};
    #pragma unroll
    for (int j = 0; j < 5; j++) {
      float wv = wreg[i * 5 + j];
      #pragma unroll
      for (int o = 0; o < 4; o++)
        a[o] += wv * rr[o + j + 2];
    }
  }

  size_t base = ((size_t)b * NC + c) * NHW + (size_t)(y0 + row) * NW + x0;
  bf16x4 gv = *(const bf16x4*)&gf16[base];
  float op[4];
  #pragma unroll
  for (int k = 0; k < 4; k++) {
    float gvv = bf2f((unsigned short)gv[k]);
    float sl = a[k] / (1.f + __expf(-a[k]));
    float sg = 1.f / (1.f + __expf(-gvv));
    op[k] = sl * sg * gvv;
  }
  uint2 ov;
  ov.x = cvtpk(op[0], op[1]);
  ov.y = cvtpk(op[2], op[3]);
  *(uint2*)&t16[base] = ov;
}

// ---------------------------------------------------------------------------
extern "C" void kernel_launch(void* const* d_in, const int* in_sizes, int n_in,
                              void* d_out, int out_size, void* d_ws, size_t ws_size,
                              hipStream_t stream) {
  const float* x       = (const float*)d_in[0];
  const float* q_w     = (const float*)d_in[1];
  const float* q_b     = (const float*)d_in[2];
  const float* kv_w    = (const float*)d_in[3];
  const float* kv_b    = (const float*)d_in[4];
  const float* local_w = (const float*)d_in[5];
  const float* local_b = (const float*)d_in[6];
  const float* mixer_w = (const float*)d_in[7];
  const float* mixer_b = (const float*)d_in[8];
  const float* p0_w    = (const float*)d_in[9];
  const float* p0_b    = (const float*)d_in[10];
  const float* bn0_g   = (const float*)d_in[11];
  const float* bn0_b   = (const float*)d_in[12];
  const float* bn0_m   = (const float*)d_in[13];
  const float* bn0_v   = (const float*)d_in[14];
  const float* lin0_w  = (const float*)d_in[15];
  const float* lin0_b  = (const float*)d_in[16];
  const float* p1_w    = (const float*)d_in[17];
  const float* p1_b    = (const float*)d_in[18];
  const float* bn1_g   = (const float*)d_in[19];
  const float* bn1_b   = (const float*)d_in[20];
  const float* bn1_m   = (const float*)d_in[21];
  const float* bn1_v   = (const float*)d_in[22];

  float* ws = (float*)d_ws;
  unsigned short* q16 = (unsigned short*)ws;               // 8,388,608 shorts
  unsigned short* gf16 = (unsigned short*)(ws + 4194304);  // 8,388,608 shorts
  unsigned short* t16 = (unsigned short*)(ws + 8388608);   // 8,388,608 shorts
  float* p0   = ws + 12582912;                     // 2,097,152
  float* lin0b= ws + 14680064;                     // 2,097,152
  float* p1   = ws + 16777216;                     // 524,288
  float* kvb  = ws + 17301504;                     // 1,048,576
  short* kT   = (short*)(ws + 18350080);           // 524,288 shorts
  short* vT   = kT + 524288;                       // 524,288 shorts
  unsigned short* wbf = (unsigned short*)(ws + 18874368);  // 81,920 shorts

  // 0) convert weights to bf16 once
  wcvt<<<dim3(80), 256, 0, stream>>>(q_w, lin0_w, kv_w, mixer_w, wbf);
  // 1) q16 = bf16(pw(x, q_w) + q_b)
  pw_gemm_mfma<false, true><<<dim3(NHW / 128, 1, NB), 256, 0, stream>>>(
      wbf, q_b, x, q16, NHW, 128);
  // 2) p0 = bn0(dw5x5_s2(x) + p0_b)          -> 64x64
  dw5x5s2_tile<128, 128, 64, 16, 140><<<dim3(4, NC, NB), 256, 0, stream>>>(
      x, p0_w, p0_b, bn0_g, bn0_b, bn0_m, bn0_v, p0);
  // 3) lin0 = pw(p0, lin0_w) + lin0_b
  pw_gemm_mfma<false, false><<<dim3(4096 / 128, 1, NB), 256, 0, stream>>>(
      wbf + 16384, lin0_b, p0, lin0b, 4096, 128);
  // 4) p1 = bn1(dw5x5_s2(lin0) + p1_b)       -> 32x32
  dw5x5s2_tile<64, 64, 32, 32, 76><<<dim3(1, NC, NB), 256, 0, stream>>>(
      lin0b, p1_w, p1_b, bn1_g, bn1_b, bn1_m, bn1_v, p1);
  // 5) kv = pw(p1, kv_w) + kv_b   (256 out channels)
  pw_gemm_mfma<false, false><<<dim3(NKV / 128, 2, NB), 256, 0, stream>>>(
      wbf + 32768, kv_b, p1, kvb, NKV, 256);
  // 6) kv -> bf16 kT [bh][kpos][32], vT [bh][d][kpos]
  kv_prep<<<dim3(4, 4, NB), 256, 0, stream>>>(kvb, kT, vT);
  // 7) split-K MFMA attention -> gf16   (4 waves: 2 qgroups x 2 key halves)
  attn_mfma64<<<dim3(NHW / 128, 4, NB), 256, 0, stream>>>(q16, kT, vT, gf16);
  // 8) lf dwconv + elementwise fuse -> t16 (bf16)
  lf_fuse_tile<<<dim3(16, NC, NB), 256, 0, stream>>>(q16, gf16, local_w, local_b, t16);
  // 9) out = pw(t16, mixer_w) + mixer_b
  pw_gemm_mfma<true, false><<<dim3(NHW / 128, 1, NB), 256, 0, stream>>>(
      wbf + 65536, mixer_b, t16, (float*)d_out, NHW, 128);
}

// Round 12
// 150.611 us; speedup vs baseline: 1.1221x; 1.1221x over previous
//
#include <hip/hip_runtime.h>
#include <hip/hip_bf16.h>
#include <math.h>

// ---------------------------------------------------------------------------
// FASA pipeline for MI355X. B=4, C=128, H=W=128, HEADS=4, dh=32, pool->32x32
// Round 12: R10 base (512-thr split-K attn, LDS-staged GEMMs) + gf16 +
// in-wave A/B software pipelining + s_setprio around MFMA clusters.
// ---------------------------------------------------------------------------

#define NB   4
#define NC   128
#define NH   128
#define NW   128
#define NHW  16384      // 128*128
#define NKV  1024       // 32*32

typedef float    f32x4  __attribute__((ext_vector_type(4)));
typedef float    f32x16 __attribute__((ext_vector_type(16)));
typedef short    bf16x8 __attribute__((ext_vector_type(8)));
typedef short    bf16x4 __attribute__((ext_vector_type(4)));
typedef unsigned u32x4v __attribute__((ext_vector_type(4)));

__device__ __forceinline__ unsigned short f2bf(float f) {
  unsigned u = __float_as_uint(f);
  u += 0x7FFF + ((u >> 16) & 1);      // round to nearest even
  return (unsigned short)(u >> 16);
}

__device__ __forceinline__ float bf2f(unsigned short u) {
  return __uint_as_float((unsigned)u << 16);
}

// pack two f32 -> bf16x2 in one instr (no builtin on gfx950; T12 recipe)
__device__ __forceinline__ unsigned cvtpk(float lo, float hi) {
  unsigned r;
  asm("v_cvt_pk_bf16_f32 %0, %1, %2" : "=v"(r) : "v"(lo), "v"(hi));
  return r;
}

// ---------------------------------------------------------------------------
// MFMA pointwise 1x1 conv: Y[b][m][n] = bias[m] + sum_c W[m][c] X[b][c][n]
// W staged to LDS as bf16 (R10-proven). IN_BF16/OUT_BF16 select X/Y dtypes.
// ---------------------------------------------------------------------------
template<bool IN_BF16, bool OUT_BF16>
__global__ __launch_bounds__(256) void pw_gemm_mfma(
    const float* __restrict__ Wmat,   // [Mtot][128] fp32
    const float* __restrict__ bias,   // [Mtot]
    const void* __restrict__ Xv,      // [B][128][npos]
    void* __restrict__ Yv,            // [B][Mtot][npos]
    int npos, int Mtot)
{
  __shared__ short Wlds[128 * 136];

  const int t  = threadIdx.x;
  const int w    = t >> 6;
  const int lane = t & 63;
  const int nl   = lane & 31;
  const int hi   = lane >> 5;
  const int b  = blockIdx.z;
  const int m0 = blockIdx.y * 128;
  const int n0 = blockIdx.x * 128;

  for (int i = t; i < 128 * 32; i += 256) {
    int row = i >> 5, c4 = (i & 31) * 4;
    float4 wv = *(const float4*)&Wmat[(size_t)(m0 + row) * 128 + c4];
    uint2 pk; pk.x = cvtpk(wv.x, wv.y); pk.y = cvtpk(wv.z, wv.w);
    *(uint2*)&Wlds[row * 136 + c4] = pk;
  }
  __syncthreads();

  f32x16 acc[4];
  #pragma unroll
  for (int mg = 0; mg < 4; mg++)
    #pragma unroll
    for (int r = 0; r < 16; r++) acc[mg][r] = 0.f;

  #pragma unroll
  for (int s = 0; s < 8; s++) {
    bf16x8 bfrag;
    if constexpr (IN_BF16) {
      const unsigned short* Xb = (const unsigned short*)Xv
          + (size_t)b * 128 * npos + n0 + w * 32 + nl;
      const unsigned short* xp = Xb + (size_t)(s * 16 + hi * 8) * npos;
      #pragma unroll
      for (int e = 0; e < 8; e++) bfrag[e] = (short)xp[(size_t)e * npos];
    } else {
      const float* Xb = (const float*)Xv + (size_t)b * 128 * npos + n0 + w * 32 + nl;
      const float* xp = Xb + (size_t)(s * 16 + hi * 8) * npos;
      float xv[8];
      #pragma unroll
      for (int e = 0; e < 8; e++) xv[e] = xp[(size_t)e * npos];
      u32x4v bu;
      #pragma unroll
      for (int j = 0; j < 4; j++) bu[j] = cvtpk(xv[2 * j], xv[2 * j + 1]);
      bfrag = __builtin_bit_cast(bf16x8, bu);
    }

    #pragma unroll
    for (int mg = 0; mg < 4; mg++) {
      bf16x8 afrag = *(const bf16x8*)&Wlds[(mg * 32 + nl) * 136 + s * 16 + hi * 8];
      acc[mg] = __builtin_amdgcn_mfma_f32_32x32x16_bf16(afrag, bfrag, acc[mg], 0, 0, 0);
    }
  }

  #pragma unroll
  for (int mg = 0; mg < 4; mg++)
    #pragma unroll
    for (int r = 0; r < 16; r++) {
      int drow = mg * 32 + (r & 3) + 8 * (r >> 2) + 4 * hi;
      float val = acc[mg][r] + bias[m0 + drow];
      if constexpr (OUT_BF16) {
        unsigned short* Yb = (unsigned short*)Yv
            + ((size_t)b * Mtot + m0) * npos + n0 + w * 32 + nl;
        Yb[(size_t)drow * npos] = f2bf(val);
      } else {
        float* Yb = (float*)Yv + ((size_t)b * Mtot + m0) * npos + n0 + w * 32 + nl;
        Yb[(size_t)drow * npos] = val;
      }
    }
}

// ---------------------------------------------------------------------------
// LDS-tiled stride-2 depthwise 5x5 + BN.
// ---------------------------------------------------------------------------
template<int INH, int INW, int OUTW, int ORPB, int WLSP>
__global__ __launch_bounds__(256) void dw5x5s2_tile(
    const float* __restrict__ in,
    const float* __restrict__ wt, const float* __restrict__ bias,
    const float* __restrict__ g, const float* __restrict__ bt,
    const float* __restrict__ mean, const float* __restrict__ var,
    float* __restrict__ out)
{
  constexpr int IR = 2 * ORPB + 3;
  constexpr int XG = OUTW / 4;
  __shared__ float Ls[IR * WLSP];

  const int t  = threadIdx.x;
  const int c  = blockIdx.y, b = blockIdx.z;
  const int y0 = blockIdx.x * ORPB;
  const float* plane = in + ((size_t)b * NC + c) * INH * INW;

  for (int i = t; i < IR * WLSP / 4; i += 256)
    *(float4*)&Ls[i * 4] = (float4){0.f, 0.f, 0.f, 0.f};
  __syncthreads();

  for (int i = t; i < IR * (INW / 4); i += 256) {
    int r = i / (INW / 4), s4 = (i % (INW / 4)) * 4;
    int gy = 2 * y0 - 2 + r;
    if (gy >= 0 && gy < INH)
      *(float4*)&Ls[r * WLSP + 4 + s4] = *(const float4*)&plane[(size_t)gy * INW + s4];
  }

  float wreg[25];
  #pragma unroll
  for (int i = 0; i < 25; i++) wreg[i] = wt[c * 25 + i];
  const float sc = g[c] * rsqrtf(var[c] + 1e-5f);
  const float off = (bias[c] - mean[c]) * sc + bt[c];
  __syncthreads();

  const int row = t / XG;
  const int x0  = (t % XG) * 4;
  const int r0  = 2 * row;

  float a[4] = {0.f, 0.f, 0.f, 0.f};
  #pragma unroll
  for (int i = 0; i < 5; i++) {
    const float* lr = &Ls[(r0 + i) * WLSP + 2 * x0];
    float4 L0 = *(const float4*)&lr[0];
    float4 L1 = *(const float4*)&lr[4];
    float4 L2 = *(const float4*)&lr[8];
    float4 L3 = *(const float4*)&lr[12];
    float rr[16] = {L0.x,L0.y,L0.z,L0.w, L1.x,L1.y,L1.z,L1.w,
                    L2.x,L2.y,L2.z,L2.w, L3.x,L3.y,L3.z,L3.w};
    #pragma unroll
    for (int j = 0; j < 5; j++) {
      float wv = wreg[i * 5 + j];
      #pragma unroll
      for (int o = 0; o < 4; o++)
        a[o] += wv * rr[2 * o + j + 2];
    }
  }

  float4 ov;
  ov.x = a[0] * sc + off; ov.y = a[1] * sc + off;
  ov.z = a[2] * sc + off; ov.w = a[3] * sc + off;
  const int OH = INH / 2;
  *(float4*)&out[((size_t)b * NC + c) * OH * OUTW + (size_t)(y0 + row) * OUTW + x0] = ov;
}

// ---------------------------------------------------------------------------
// kv prep: kvb fp32 [4][256][1024] -> kT bf16 [16][1024][32], vT bf16 [16][32][1024]
// ---------------------------------------------------------------------------
__global__ __launch_bounds__(256) void kv_prep(
    const float* __restrict__ kvb,
    short* __restrict__ kT, short* __restrict__ vT)
{
  const int t = threadIdx.x;
  const int h = blockIdx.y, b = blockIdx.z;
  const int kpos = blockIdx.x * 256 + t;
  const int bh = b * 4 + h;

  bf16x8 kr[4];
  #pragma unroll
  for (int d = 0; d < 32; d++) {
    float kvv = kvb[((size_t)b * 256 + h * 32 + d) * NKV + kpos];
    float vvv = kvb[((size_t)b * 256 + 128 + h * 32 + d) * NKV + kpos];
    kr[d >> 3][d & 7] = (short)f2bf(kvv);
    vT[(size_t)bh * 32768 + d * NKV + kpos] = (short)f2bf(vvv);
  }
  short* dstk = kT + (size_t)bh * 32768 + (size_t)kpos * 32;
  #pragma unroll
  for (int i = 0; i < 4; i++)
    *(bf16x8*)(dstk + i * 8) = kr[i];
}

// ---------------------------------------------------------------------------
// Split-K dual-query 32x32 MFMA flash attention, 512 thr = 8 waves:
// wave w -> query group (w&3, 64 q), key half (w>>2).
// In-wave A/B software pipeline: both QK^T MFMA pairs issued before softmax A,
// so softmax A overlaps B's MFMAs and softmax B overlaps A's PV MFMAs.
// setprio(1) around MFMA clusters (T5). Output gf bf16.
// ---------------------------------------------------------------------------
__global__ __launch_bounds__(512) void attn_mfma64(
    const unsigned short* __restrict__ q16,  // [4][128][16384] bf16
    const short* __restrict__ kT,            // [16][1024][32] bf16
    const short* __restrict__ vT,            // [16][32][1024] bf16
    unsigned short* __restrict__ gf16)       // [4][128][16384] bf16
{
  __shared__ float Cmb[4][64][34];

  const int t    = threadIdx.x;
  const int w    = t >> 6;          // 0..7
  const int lane = t & 63;
  const int c    = lane & 31;
  const int hi   = lane >> 5;
  const int qg   = w & 3;
  const int half = w >> 2;
  const int b    = blockIdx.z, h = blockIdx.y;
  const int q0   = blockIdx.x * 256 + qg * 64;
  const int bh   = b * 4 + h;
  const int kbase = half * 512;     // first key of this half

  const float QSCALE = 0.17677669529663689f * 1.4426950408889634f; // scale*log2e

  // Q^T B-operand frags for columns q0+c (A) and q0+32+c (B), from bf16
  bf16x8 qA1, qA2, qB1, qB2;
  {
    const unsigned short* qb = q16 + ((size_t)(b * NC + h * 32 + hi * 8)) * NHW + q0 + c;
    float fva[16], fvb[16];
    #pragma unroll
    for (int e = 0; e < 8; e++) {
      fva[e]     = bf2f(qb[(size_t)e * NHW]) * QSCALE;
      fva[8 + e] = bf2f(qb[(size_t)(16 + e) * NHW]) * QSCALE;
      fvb[e]     = bf2f(qb[(size_t)e * NHW + 32]) * QSCALE;
      fvb[8 + e] = bf2f(qb[(size_t)(16 + e) * NHW + 32]) * QSCALE;
    }
    u32x4v u1, u2, u3, u4;
    #pragma unroll
    for (int j = 0; j < 4; j++) {
      u1[j] = cvtpk(fva[2 * j], fva[2 * j + 1]);
      u2[j] = cvtpk(fva[8 + 2 * j], fva[9 + 2 * j]);
      u3[j] = cvtpk(fvb[2 * j], fvb[2 * j + 1]);
      u4[j] = cvtpk(fvb[8 + 2 * j], fvb[9 + 2 * j]);
    }
    qA1 = __builtin_bit_cast(bf16x8, u1); qA2 = __builtin_bit_cast(bf16x8, u2);
    qB1 = __builtin_bit_cast(bf16x8, u3); qB2 = __builtin_bit_cast(bf16x8, u4);
  }

  const short* kbh = kT + (size_t)bh * 32768;
  const short* vbh = vT + (size_t)bh * 32768;

  f32x16 oA, oB;
  #pragma unroll
  for (int r = 0; r < 16; r++) { oA[r] = 0.f; oB[r] = 0.f; }
  const f32x16 zf = oA;
  float lsumA = 0.f, lsumB = 0.f;

  bf16x8 ka  = *(const bf16x8*)(kbh + (size_t)(kbase + c) * 32 + hi * 8);
  bf16x8 kb2 = *(const bf16x8*)(kbh + (size_t)(kbase + c) * 32 + 16 + hi * 8);
  bf16x8 va  = *(const bf16x8*)(vbh + (size_t)c * NKV + kbase + hi * 8);
  bf16x8 vb2 = *(const bf16x8*)(vbh + (size_t)c * NKV + kbase + 16 + hi * 8);

  for (int kt = 0; kt < 16; kt++) {
    const int k0n = (kt < 15) ? (kbase + (kt + 1) * 32) : 0;
    bf16x8 nka  = *(const bf16x8*)(kbh + (size_t)(k0n + c) * 32 + hi * 8);
    bf16x8 nkb  = *(const bf16x8*)(kbh + (size_t)(k0n + c) * 32 + 16 + hi * 8);
    bf16x8 nva  = *(const bf16x8*)(vbh + (size_t)c * NKV + k0n + hi * 8);
    bf16x8 nvb  = *(const bf16x8*)(vbh + (size_t)c * NKV + k0n + 16 + hi * 8);

    // ---- both QK^T pairs up front ----
    __builtin_amdgcn_s_setprio(1);
    f32x16 sA = __builtin_amdgcn_mfma_f32_32x32x16_bf16(ka,  qA1, zf, 0, 0, 0);
    sA        = __builtin_amdgcn_mfma_f32_32x32x16_bf16(kb2, qA2, sA, 0, 0, 0);
    f32x16 sB = __builtin_amdgcn_mfma_f32_32x32x16_bf16(ka,  qB1, zf, 0, 0, 0);
    sB        = __builtin_amdgcn_mfma_f32_32x32x16_bf16(kb2, qB2, sB, 0, 0, 0);
    __builtin_amdgcn_s_setprio(0);

    // ---- softmax A (overlaps B's QK in flight) ----
    bf16x8 pbA1, pbA2;
    {
      float p[16];
      #pragma unroll
      for (int r = 0; r < 16; r++) p[r] = __builtin_amdgcn_exp2f(sA[r]);
      float s0 = (p[0] + p[1]) + (p[2] + p[3]);
      float s1 = (p[4] + p[5]) + (p[6] + p[7]);
      float s2 = (p[8] + p[9]) + (p[10] + p[11]);
      float s3 = (p[12] + p[13]) + (p[14] + p[15]);
      lsumA += (s0 + s1) + (s2 + s3);
      unsigned a0 = cvtpk(p[0],  p[1]);
      unsigned a1 = cvtpk(p[2],  p[3]);
      unsigned a2 = cvtpk(p[4],  p[5]);
      unsigned a3 = cvtpk(p[6],  p[7]);
      unsigned a4 = cvtpk(p[8],  p[9]);
      unsigned a5 = cvtpk(p[10], p[11]);
      unsigned a6 = cvtpk(p[12], p[13]);
      unsigned a7 = cvtpk(p[14], p[15]);
      asm("v_permlane32_swap_b32 %0, %1" : "+v"(a0), "+v"(a2));
      asm("v_permlane32_swap_b32 %0, %1" : "+v"(a1), "+v"(a3));
      asm("v_permlane32_swap_b32 %0, %1" : "+v"(a4), "+v"(a6));
      asm("v_permlane32_swap_b32 %0, %1" : "+v"(a5), "+v"(a7));
      u32x4v b1u = {a0, a1, a2, a3};
      u32x4v b2u = {a4, a5, a6, a7};
      pbA1 = __builtin_bit_cast(bf16x8, b1u);
      pbA2 = __builtin_bit_cast(bf16x8, b2u);
    }
    __builtin_amdgcn_s_setprio(1);
    oA = __builtin_amdgcn_mfma_f32_32x32x16_bf16(va,  pbA1, oA, 0, 0, 0);
    oA = __builtin_amdgcn_mfma_f32_32x32x16_bf16(vb2, pbA2, oA, 0, 0, 0);
    __builtin_amdgcn_s_setprio(0);

    // ---- softmax B (overlaps A's PV in flight) ----
    bf16x8 pbB1, pbB2;
    {
      float p[16];
      #pragma unroll
      for (int r = 0; r < 16; r++) p[r] = __builtin_amdgcn_exp2f(sB[r]);
      float s0 = (p[0] + p[1]) + (p[2] + p[3]);
      float s1 = (p[4] + p[5]) + (p[6] + p[7]);
      float s2 = (p[8] + p[9]) + (p[10] + p[11]);
      float s3 = (p[12] + p[13]) + (p[14] + p[15]);
      lsumB += (s0 + s1) + (s2 + s3);
      unsigned a0 = cvtpk(p[0],  p[1]);
      unsigned a1 = cvtpk(p[2],  p[3]);
      unsigned a2 = cvtpk(p[4],  p[5]);
      unsigned a3 = cvtpk(p[6],  p[7]);
      unsigned a4 = cvtpk(p[8],  p[9]);
      unsigned a5 = cvtpk(p[10], p[11]);
      unsigned a6 = cvtpk(p[12], p[13]);
      unsigned a7 = cvtpk(p[14], p[15]);
      asm("v_permlane32_swap_b32 %0, %1" : "+v"(a0), "+v"(a2));
      asm("v_permlane32_swap_b32 %0, %1" : "+v"(a1), "+v"(a3));
      asm("v_permlane32_swap_b32 %0, %1" : "+v"(a4), "+v"(a6));
      asm("v_permlane32_swap_b32 %0, %1" : "+v"(a5), "+v"(a7));
      u32x4v b1u = {a0, a1, a2, a3};
      u32x4v b2u = {a4, a5, a6, a7};
      pbB1 = __builtin_bit_cast(bf16x8, b1u);
      pbB2 = __builtin_bit_cast(bf16x8, b2u);
    }
    __builtin_amdgcn_s_setprio(1);
    oB = __builtin_amdgcn_mfma_f32_32x32x16_bf16(va,  pbB1, oB, 0, 0, 0);
    oB = __builtin_amdgcn_mfma_f32_32x32x16_bf16(vb2, pbB2, oB, 0, 0, 0);
    __builtin_amdgcn_s_setprio(0);

    ka = nka; kb2 = nkb; va = nva; vb2 = nvb;
  }

  // combine halves through LDS: half1 deposits, half0 reduces + stores
  if (half) {
    float* dst = &Cmb[qg][lane][0];
    #pragma unroll
    for (int r = 0; r < 16; r++) { dst[r] = oA[r]; dst[16 + r] = oB[r]; }
    dst[32] = lsumA; dst[33] = lsumB;
  }
  __syncthreads();
  if (!half) {
    const float* src = &Cmb[qg][lane][0];
    #pragma unroll
    for (int r = 0; r < 16; r++) { oA[r] += src[r]; oB[r] += src[16 + r]; }
    lsumA += src[32]; lsumB += src[33];

    lsumA += __shfl_xor(lsumA, 32);
    lsumB += __shfl_xor(lsumB, 32);
    float invA = 1.f / lsumA;
    float invB = 1.f / lsumB;

    unsigned short* gfb = gf16 + ((size_t)(b * NC + h * 32)) * NHW + q0 + c;
    #pragma unroll
    for (int r = 0; r < 16; r++) {
      int d = (r & 3) + 8 * (r >> 2) + 4 * hi;
      gfb[(size_t)d * NHW]      = f2bf(oA[r] * invA);
      gfb[(size_t)d * NHW + 32] = f2bf(oB[r] * invB);
    }
  }
}

// ---------------------------------------------------------------------------
// LDS-tiled lf_fuse: lf = dw5x5_s1(q16)+local_b; t16 = bf16(lf*sig(lf)*sig(gf)*gf)
// q16/gf16 bf16 inputs.
// ---------------------------------------------------------------------------
__global__ __launch_bounds__(256) void lf_fuse_tile(
    const unsigned short* __restrict__ q16, const unsigned short* __restrict__ gf16,
    const float* __restrict__ wt, const float* __restrict__ bias,
    unsigned short* __restrict__ t16)
{
  __shared__ float Ls[12 * 140];

  const int t  = threadIdx.x;
  const int c  = blockIdx.y, b = blockIdx.z;
  const int y0 = blockIdx.x * 8;
  const unsigned short* plane = q16 + ((size_t)b * NC + c) * NHW;

  for (int i = t; i < 12 * 140 / 4; i += 256)
    *(float4*)&Ls[i * 4] = (float4){0.f, 0.f, 0.f, 0.f};
  __syncthreads();

  for (int i = t; i < 12 * 16; i += 256) {
    int r = i >> 4, s8 = (i & 15) * 8;
    int gy = y0 - 2 + r;
    if (gy >= 0 && gy < NH) {
      bf16x8 v = *(const bf16x8*)&plane[(size_t)gy * NW + s8];
      float* dp = &Ls[r * 140 + 4 + s8];
      #pragma unroll
      for (int j = 0; j < 8; j++) dp[j] = bf2f((unsigned short)v[j]);
    }
  }

  float wreg[25];
  #pragma unroll
  for (int i = 0; i < 25; i++) wreg[i] = wt[c * 25 + i];
  const float bs = bias[c];
  __syncthreads();

  const int row = t >> 5;
  const int x0  = (t & 31) * 4;

  float a[4] = {bs, bs, bs, bs};
  #pragma unroll
  for (int i = 0; i < 5; i++) {
    const float* lr = &Ls[(row + i) * 140 + x0];
    float4 L0 = *(const float4*)&lr[0];
    float4 L1 = *(const float4*)&lr[4];
    float4 L2 = *(const float4*)&lr[8];
    float rr[12] = {L0.x,L0.y,L0.z,L0.w, L1.x,L1.y,L1.z,L1.w,
                    L2.x,L2.y,L2.z,L2.w};
    #pragma unroll
    for (int j = 0; j < 5; j++) {
      float wv = wreg[i * 5 + j];
      #pragma unroll
      for (int o = 0; o < 4; o++)
        a[o] += wv * rr[o + j + 2];
    }
  }

  size_t base = ((size_t)b * NC + c) * NHW + (size_t)(y0 + row) * NW + x0;
  bf16x4 gv = *(const bf16x4*)&gf16[base];
  float op[4];
  #pragma unroll
  for (int k = 0; k < 4; k++) {
    float gvv = bf2f((unsigned short)gv[k]);
    float sl = a[k] / (1.f + __expf(-a[k]));
    float sg = 1.f / (1.f + __expf(-gvv));
    op[k] = sl * sg * gvv;
  }
  uint2 ov;
  ov.x = cvtpk(op[0], op[1]);
  ov.y = cvtpk(op[2], op[3]);
  *(uint2*)&t16[base] = ov;
}

// ---------------------------------------------------------------------------
extern "C" void kernel_launch(void* const* d_in, const int* in_sizes, int n_in,
                              void* d_out, int out_size, void* d_ws, size_t ws_size,
                              hipStream_t stream) {
  const float* x       = (const float*)d_in[0];
  const float* q_w     = (const float*)d_in[1];
  const float* q_b     = (const float*)d_in[2];
  const float* kv_w    = (const float*)d_in[3];
  const float* kv_b    = (const float*)d_in[4];
  const float* local_w = (const float*)d_in[5];
  const float* local_b = (const float*)d_in[6];
  const float* mixer_w = (const float*)d_in[7];
  const float* mixer_b = (const float*)d_in[8];
  const float* p0_w    = (const float*)d_in[9];
  const float* p0_b    = (const float*)d_in[10];
  const float* bn0_g   = (const float*)d_in[11];
  const float* bn0_b   = (const float*)d_in[12];
  const float* bn0_m   = (const float*)d_in[13];
  const float* bn0_v   = (const float*)d_in[14];
  const float* lin0_w  = (const float*)d_in[15];
  const float* lin0_b  = (const float*)d_in[16];
  const float* p1_w    = (const float*)d_in[17];
  const float* p1_b    = (const float*)d_in[18];
  const float* bn1_g   = (const float*)d_in[19];
  const float* bn1_b   = (const float*)d_in[20];
  const float* bn1_m   = (const float*)d_in[21];
  const float* bn1_v   = (const float*)d_in[22];

  float* ws = (float*)d_ws;
  unsigned short* q16 = (unsigned short*)ws;               // 8,388,608 shorts
  unsigned short* gf16 = (unsigned short*)(ws + 4194304);  // 8,388,608 shorts
  unsigned short* t16 = (unsigned short*)(ws + 8388608);   // 8,388,608 shorts
  float* p0   = ws + 12582912;                     // 2,097,152
  float* lin0b= ws + 14680064;                     // 2,097,152
  float* p1   = ws + 16777216;                     // 524,288
  float* kvb  = ws + 17301504;                     // 1,048,576
  short* kT   = (short*)(ws + 18350080);           // 524,288 shorts
  short* vT   = kT + 524288;                       // 524,288 shorts

  // 1) q16 = bf16(pw(x, q_w) + q_b)
  pw_gemm_mfma<false, true><<<dim3(NHW / 128, 1, NB), 256, 0, stream>>>(
      q_w, q_b, x, q16, NHW, 128);
  // 2) p0 = bn0(dw5x5_s2(x) + p0_b)          -> 64x64
  dw5x5s2_tile<128, 128, 64, 16, 140><<<dim3(4, NC, NB), 256, 0, stream>>>(
      x, p0_w, p0_b, bn0_g, bn0_b, bn0_m, bn0_v, p0);
  // 3) lin0 = pw(p0, lin0_w) + lin0_b
  pw_gemm_mfma<false, false><<<dim3(4096 / 128, 1, NB), 256, 0, stream>>>(
      lin0_w, lin0_b, p0, lin0b, 4096, 128);
  // 4) p1 = bn1(dw5x5_s2(lin0) + p1_b)       -> 32x32
  dw5x5s2_tile<64, 64, 32, 32, 76><<<dim3(1, NC, NB), 256, 0, stream>>>(
      lin0b, p1_w, p1_b, bn1_g, bn1_b, bn1_m, bn1_v, p1);
  // 5) kv = pw(p1, kv_w) + kv_b   (256 out channels)
  pw_gemm_mfma<false, false><<<dim3(NKV / 128, 2, NB), 256, 0, stream>>>(
      kv_w, kv_b, p1, kvb, NKV, 256);
  // 6) kv -> bf16 kT [bh][kpos][32], vT [bh][d][kpos]
  kv_prep<<<dim3(4, 4, NB), 256, 0, stream>>>(kvb, kT, vT);
  // 7) split-K MFMA attention -> gf16   (8 waves: 4 qgroups x 2 key halves)
  attn_mfma64<<<dim3(NHW / 256, 4, NB), 512, 0, stream>>>(q16, kT, vT, gf16);
  // 8) lf dwconv + elementwise fuse -> t16 (bf16)
  lf_fuse_tile<<<dim3(16, NC, NB), 256, 0, stream>>>(q16, gf16, local_w, local_b, t16);
  // 9) out = pw(t16, mixer_w) + mixer_b
  pw_gemm_mfma<true, false><<<dim3(NHW / 128, 1, NB), 256, 0, stream>>>(
      mixer_w, mixer_b, t16, (float*)d_out, NHW, 128);
}